// Round 3
// baseline (464.263 us; speedup 1.0000x reference)
//
#include <hip/hip_runtime.h>

typedef float v2f __attribute__((ext_vector_type(2)));

#define HIDDEN 64
#define HALFD  32
#define VOCAB  64
#define BATCH  256
#define SEQLEN 2048

static __device__ __forceinline__ v2f fma2(v2f a, v2f b, v2f c) {
    return __builtin_elementwise_fma(a, b, c);
}

// ---------------------------------------------------------------------------
// Kernel 1: per-token vocab tables.
//   ws[0    ..2047]  ks_voc [64][32]  (normalized hs)
//   ws[2048 ..4095]  ke_voc [64][32]  (normalized he)
//   ws[4096 ..6143]  vs_voc [64][32]  (raw hs)
//   ws[6144 ..8191]  ve_voc [64][32]  (raw he)
//   ws[8192 ..12287] Gs [64][64]      (written by gram_kernel)
//   ws[12288..16383] Ge [64][64]
// ---------------------------------------------------------------------------
__global__ __launch_bounds__(64) void vocab_kernel(
    const float* __restrict__ embed, const float* __restrict__ W1, const float* __restrict__ b1,
    const float* __restrict__ W2, const float* __restrict__ b2,
    const float* __restrict__ ln_g, const float* __restrict__ ln_b,
    const float* __restrict__ Ws, const float* __restrict__ bs,
    const float* __restrict__ We, const float* __restrict__ be,
    float* __restrict__ ws)
{
    const int v = blockIdx.x;
    const int tid = threadIdx.x;

    __shared__ float e_s[64];
    __shared__ float a1_s[128];
    __shared__ float h_s[64];

    e_s[tid] = embed[v * 64 + tid];
    __syncthreads();

    float acc0 = b1[tid], acc1 = b1[tid + 64];
    #pragma unroll 8
    for (int m = 0; m < 64; ++m) {
        float ev = e_s[m];
        acc0 = fmaf(ev, W1[tid * 64 + m], acc0);
        acc1 = fmaf(ev, W1[(tid + 64) * 64 + m], acc1);
    }
    a1_s[tid]      = fmaxf(acc0, 0.0f);
    a1_s[tid + 64] = fmaxf(acc1, 0.0f);
    __syncthreads();

    float ff = b2[tid];
    #pragma unroll 8
    for (int m = 0; m < 128; ++m) ff = fmaf(a1_s[m], W2[tid * 128 + m], ff);
    float x = e_s[tid] + ff;

    float s = x, s2 = x * x;
    #pragma unroll
    for (int off = 32; off >= 1; off >>= 1) {
        s  += __shfl_xor(s,  off, 64);
        s2 += __shfl_xor(s2, off, 64);
    }
    float mu  = s * (1.0f / 64.0f);
    float var = s2 * (1.0f / 64.0f) - mu * mu;
    float hval = (x - mu) * rsqrtf(var + 1e-5f) * ln_g[tid] + ln_b[tid];
    h_s[tid] = hval;
    __syncthreads();

    const int j = tid & 31;
    const bool is_s = tid < 32;
    const float* W = is_s ? Ws : We;
    float acc = is_s ? bs[j] : be[j];
    #pragma unroll 8
    for (int m = 0; m < 64; ++m) acc = fmaf(h_s[m], W[j * 64 + m], acc);

    float n2 = acc * acc;
    #pragma unroll
    for (int off = 16; off >= 1; off >>= 1) n2 += __shfl_xor(n2, off, 64);
    float norm = sqrtf(n2);
    float kn = acc / fmaxf(norm, 1e-12f);

    const int base = v * 32 + j;
    if (is_s) { ws[base]        = kn; ws[4096 + base] = acc; }
    else      { ws[2048 + base] = kn; ws[6144 + base] = acc; }
}

// ---------------------------------------------------------------------------
// Kernel 1b: Gram tables G_w[a][b] = k_w[a] . k_w[b]  (64x64 per branch)
// ---------------------------------------------------------------------------
__global__ __launch_bounds__(256) void gram_kernel(float* __restrict__ ws)
{
    const int w = blockIdx.x;        // 0: s, 1: e
    const int tid = threadIdx.x;
    __shared__ float k_s[2048];
    const float* kb = ws + w * 2048;
    for (int i = tid; i < 2048; i += 256) k_s[i] = kb[i];
    __syncthreads();
    const int a  = tid >> 2;
    const int b0 = (tid & 3) << 4;
    float* Gw = ws + 8192 + w * 4096 + a * 64;
    for (int bb = 0; bb < 16; ++bb) {
        const int bcol = b0 + bb;
        float acc = 0.f;
        #pragma unroll
        for (int m = 0; m < 32; ++m) acc = fmaf(k_s[a * 32 + m], k_s[bcol * 32 + m], acc);
        Gw[bcol] = acc;
    }
}

// ---------------------------------------------------------------------------
// Kernel 2: chunked (n=4) WY delta-rule scan.
// One 64-lane wave per batch; lane l<32 owns M_s row l, lane l>=32 owns M_e
// row l-32 (full 32-float row in VGPRs as 16 float2).
// Per chunk: matvec phase (4-way ILP) -> scalar d-recurrence (depth 4) ->
// axpy phase (16 chains) with rolling key reload for the next chunk.
// ---------------------------------------------------------------------------
__global__ __launch_bounds__(64) void scan_kernel(
    const int* __restrict__ seq, const float* __restrict__ ws,
    const float* __restrict__ Wrp, const float* __restrict__ brp,
    const float* __restrict__ Wo, const float* __restrict__ bo,
    float* __restrict__ out)
{
    const int b    = blockIdx.x;
    const int lane = threadIdx.x;      // 0..63
    const int row  = lane & 31;
    const int w    = lane >> 5;        // 0: s, 1: e

    __shared__ float4 smem4[4096];     // 64 KB: k(16K) | v(16K) | G(32K)
    float* const kT = (float*)smem4;
    float* const vT = kT + 4096;
    float* const GT = kT + 8192;

    {
        const float4* ws4 = (const float4*)ws;
        for (int i = lane; i < 4096; i += 64) smem4[i] = ws4[i];
    }
    __syncthreads();

    const float* kw = kT + w * 2048;
    const float* vw = vT + w * 2048;
    const float* Gw = GT + w * 4096;

    v2f M[16];
    #pragma unroll
    for (int j = 0; j < 16; ++j) { v2f z = {0.f, 0.f}; M[j] = z; }

    v2f K[4][16];
    float vv0, vv1, vv2, vv3;
    float g01, g02, g03, g12, g13, g23;

    const int4* sq4 = (const int4*)(seq + b * SEQLEN);
    int4 tkC = sq4[0];
    int4 tkN = sq4[1];

    auto loadK = [&](int slot, int tok) {
        const float4* kp = (const float4*)(kw + tok * 32);
        #pragma unroll
        for (int j = 0; j < 8; ++j) {
            union { float4 f4; v2f h[2]; } u;
            u.f4 = kp[j];
            K[slot][2 * j]     = u.h[0];
            K[slot][2 * j + 1] = u.h[1];
        }
    };

    auto dotK = [&](const v2f (&Kt)[16]) -> float {
        v2f q0 = M[0] * Kt[0], q1 = M[1] * Kt[1], q2 = M[2] * Kt[2], q3 = M[3] * Kt[3];
        #pragma unroll
        for (int j = 4; j < 16; j += 4) {
            q0 = fma2(M[j],     Kt[j],     q0);
            q1 = fma2(M[j + 1], Kt[j + 1], q1);
            q2 = fma2(M[j + 2], Kt[j + 2], q2);
            q3 = fma2(M[j + 3], Kt[j + 3], q3);
        }
        v2f qs = (q0 + q1) + (q2 + q3);
        return qs.x + qs.y;
    };

    // prologue: chunk-0 keys / Gram scalars / values
    loadK(0, tkC.x); loadK(1, tkC.y); loadK(2, tkC.z); loadK(3, tkC.w);
    g01 = Gw[tkC.x * 64 + tkC.y]; g02 = Gw[tkC.x * 64 + tkC.z]; g03 = Gw[tkC.x * 64 + tkC.w];
    g12 = Gw[tkC.y * 64 + tkC.z]; g13 = Gw[tkC.y * 64 + tkC.w]; g23 = Gw[tkC.z * 64 + tkC.w];
    vv0 = vw[tkC.x * 32 + row]; vv1 = vw[tkC.y * 32 + row];
    vv2 = vw[tkC.z * 32 + row]; vv3 = vw[tkC.w * 32 + row];

    const float invL = 1.0f / (float)SEQLEN;
    const bool  is_e = (w == 1);

    for (int c = 0; c < 511; ++c) {
        // matvec vs chunk-start M (independent across t -> ILP)
        float c0 = dotK(K[0]);
        float c1 = dotK(K[1]);
        float c2 = dotK(K[2]);
        float c3 = dotK(K[3]);

        // scalar d-recurrence with Gram corrections (exact)
        float fb = (float)(4 * c + 1) * invL;
        float f0 = is_e ? fb             : 1.0f;
        float f1 = is_e ? fb + invL      : 1.0f;
        float f2 = is_e ? fb + 2 * invL  : 1.0f;
        float f3 = is_e ? fb + 3 * invL  : 1.0f;
        float d0 = f0 * (vv0 - c0);
        float d1 = f1 * (vv1 - c1 - g01 * d0);
        float d2 = f2 * (vv2 - c2 - (g02 * d0 + g12 * d1));
        float d3 = f3 * (vv3 - c3 - ((g03 * d0 + g13 * d1) + g23 * d2));

        v2f D0 = {d0, d0}, D1 = {d1, d1}, D2 = {d2, d2}, D3 = {d3, d3};

        // axpy; each K[t] is reloaded for the NEXT chunk right after last use
        #pragma unroll
        for (int j = 0; j < 16; ++j) M[j] = fma2(D0, K[0][j], M[j]);
        loadK(0, tkN.x);
        #pragma unroll
        for (int j = 0; j < 16; ++j) M[j] = fma2(D1, K[1][j], M[j]);
        loadK(1, tkN.y);
        #pragma unroll
        for (int j = 0; j < 16; ++j) M[j] = fma2(D2, K[2][j], M[j]);
        loadK(2, tkN.z);
        #pragma unroll
        for (int j = 0; j < 16; ++j) M[j] = fma2(D3, K[3][j], M[j]);
        loadK(3, tkN.w);

        // prefetch next chunk's Gram scalars + values
        g01 = Gw[tkN.x * 64 + tkN.y]; g02 = Gw[tkN.x * 64 + tkN.z]; g03 = Gw[tkN.x * 64 + tkN.w];
        g12 = Gw[tkN.y * 64 + tkN.z]; g13 = Gw[tkN.y * 64 + tkN.w]; g23 = Gw[tkN.z * 64 + tkN.w];
        vv0 = vw[tkN.x * 32 + row]; vv1 = vw[tkN.y * 32 + row];
        vv2 = vw[tkN.z * 32 + row]; vv3 = vw[tkN.w * 32 + row];

        tkC = tkN;
        int cn = c + 2; cn = cn > 511 ? 511 : cn;
        tkN = sq4[cn];
    }

    // final partial chunk: steps 2044..2046 write; token 2047 is the query.
    // r = M_2047 . q = c3 + g03*d0 + g13*d1 + g23*d2  (no axpy needed)
    float r;
    {
        float c0 = dotK(K[0]);
        float c1 = dotK(K[1]);
        float c2 = dotK(K[2]);
        float c3 = dotK(K[3]);
        float fb = (float)(2044 + 1) * invL;
        float f0 = is_e ? fb            : 1.0f;
        float f1 = is_e ? fb + invL     : 1.0f;
        float f2 = is_e ? fb + 2 * invL : 1.0f;
        float d0 = f0 * (vv0 - c0);
        float d1 = f1 * (vv1 - c1 - g01 * d0);
        float d2 = f2 * (vv2 - c2 - (g02 * d0 + g12 * d1));
        r = c3 + (g03 * d0 + g13 * d1) + g23 * d2;
    }

    __syncthreads();
    float* r_s  = vT;          // reuse v region (no longer needed)
    float* t1_s = vT + 64;
    r_s[lane] = r;
    __syncthreads();

    // out = (r @ Wrp.T + brp) @ Wo.T + bo
    {
        float acc = brp[lane];
        #pragma unroll 8
        for (int m = 0; m < 64; ++m) acc = fmaf(Wrp[lane * 64 + m], r_s[m], acc);
        t1_s[lane] = acc;
    }
    __syncthreads();
    {
        float acc = bo[lane];
        #pragma unroll 8
        for (int m = 0; m < 64; ++m) acc = fmaf(Wo[lane * 64 + m], t1_s[m], acc);
        out[b * 64 + lane] = acc;
    }
}

extern "C" void kernel_launch(void* const* d_in, const int* in_sizes, int n_in,
                              void* d_out, int out_size, void* d_ws, size_t ws_size,
                              hipStream_t stream)
{
    const int*   seq   = (const int*)  d_in[0];
    const float* embed = (const float*)d_in[1];
    const float* W1    = (const float*)d_in[2];
    const float* b1    = (const float*)d_in[3];
    const float* W2    = (const float*)d_in[4];
    const float* b2    = (const float*)d_in[5];
    const float* ln_g  = (const float*)d_in[6];
    const float* ln_b  = (const float*)d_in[7];
    const float* Ws    = (const float*)d_in[8];
    const float* bs    = (const float*)d_in[9];
    const float* We    = (const float*)d_in[10];
    const float* be    = (const float*)d_in[11];
    const float* Wrp   = (const float*)d_in[12];
    const float* brp   = (const float*)d_in[13];
    const float* Wo    = (const float*)d_in[14];
    const float* bo    = (const float*)d_in[15];
    float* ws  = (float*)d_ws;
    float* out = (float*)d_out;

    hipLaunchKernelGGL(vocab_kernel, dim3(VOCAB), dim3(64), 0, stream,
                       embed, W1, b1, W2, b2, ln_g, ln_b, Ws, bs, We, be, ws);
    hipLaunchKernelGGL(gram_kernel, dim3(2), dim3(256), 0, stream, ws);
    hipLaunchKernelGGL(scan_kernel, dim3(BATCH), dim3(64), 0, stream,
                       seq, ws, Wrp, brp, Wo, bo, out);
}

// Round 4
// 416.822 us; speedup vs baseline: 1.1138x; 1.1138x over previous
//
#include <hip/hip_runtime.h>

typedef float v2f __attribute__((ext_vector_type(2)));

#define HIDDEN 64
#define HALFD  32
#define VOCAB  64
#define BATCH  256
#define SEQLEN 2048

static __device__ __forceinline__ v2f fma2(v2f a, v2f b, v2f c) {
    return __builtin_elementwise_fma(a, b, c);
}

// ---------------------------------------------------------------------------
// Kernel 1: per-token vocab tables.
//   ws[0    ..2047]  ks_voc [64][32]  (normalized hs)
//   ws[2048 ..4095]  ke_voc [64][32]  (normalized he)
//   ws[4096 ..6143]  vs_voc [64][32]  (raw hs)
//   ws[6144 ..8191]  ve_voc [64][32]  (raw he)
//   ws[8192 ..12287] Gs [64][64]      (written by gram_kernel)
//   ws[12288..16383] Ge [64][64]
// ---------------------------------------------------------------------------
__global__ __launch_bounds__(64) void vocab_kernel(
    const float* __restrict__ embed, const float* __restrict__ W1, const float* __restrict__ b1,
    const float* __restrict__ W2, const float* __restrict__ b2,
    const float* __restrict__ ln_g, const float* __restrict__ ln_b,
    const float* __restrict__ Ws, const float* __restrict__ bs,
    const float* __restrict__ We, const float* __restrict__ be,
    float* __restrict__ ws)
{
    const int v = blockIdx.x;
    const int tid = threadIdx.x;

    __shared__ float e_s[64];
    __shared__ float a1_s[128];
    __shared__ float h_s[64];

    e_s[tid] = embed[v * 64 + tid];
    __syncthreads();

    float acc0 = b1[tid], acc1 = b1[tid + 64];
    #pragma unroll 8
    for (int m = 0; m < 64; ++m) {
        float ev = e_s[m];
        acc0 = fmaf(ev, W1[tid * 64 + m], acc0);
        acc1 = fmaf(ev, W1[(tid + 64) * 64 + m], acc1);
    }
    a1_s[tid]      = fmaxf(acc0, 0.0f);
    a1_s[tid + 64] = fmaxf(acc1, 0.0f);
    __syncthreads();

    float ff = b2[tid];
    #pragma unroll 8
    for (int m = 0; m < 128; ++m) ff = fmaf(a1_s[m], W2[tid * 128 + m], ff);
    float x = e_s[tid] + ff;

    float s = x, s2 = x * x;
    #pragma unroll
    for (int off = 32; off >= 1; off >>= 1) {
        s  += __shfl_xor(s,  off, 64);
        s2 += __shfl_xor(s2, off, 64);
    }
    float mu  = s * (1.0f / 64.0f);
    float var = s2 * (1.0f / 64.0f) - mu * mu;
    float hval = (x - mu) * rsqrtf(var + 1e-5f) * ln_g[tid] + ln_b[tid];
    h_s[tid] = hval;
    __syncthreads();

    const int j = tid & 31;
    const bool is_s = tid < 32;
    const float* W = is_s ? Ws : We;
    float acc = is_s ? bs[j] : be[j];
    #pragma unroll 8
    for (int m = 0; m < 64; ++m) acc = fmaf(h_s[m], W[j * 64 + m], acc);

    float n2 = acc * acc;
    #pragma unroll
    for (int off = 16; off >= 1; off >>= 1) n2 += __shfl_xor(n2, off, 64);
    float norm = sqrtf(n2);
    float kn = acc / fmaxf(norm, 1e-12f);

    const int base = v * 32 + j;
    if (is_s) { ws[base]        = kn; ws[4096 + base] = acc; }
    else      { ws[2048 + base] = kn; ws[6144 + base] = acc; }
}

// ---------------------------------------------------------------------------
// Kernel 1b: Gram tables G_w[a][b] = k_w[a] . k_w[b]  (64x64 per branch)
// ---------------------------------------------------------------------------
__global__ __launch_bounds__(256) void gram_kernel(float* __restrict__ ws)
{
    const int w = blockIdx.x;        // 0: s, 1: e
    const int tid = threadIdx.x;
    __shared__ float k_s[2048];
    const float* kb = ws + w * 2048;
    for (int i = tid; i < 2048; i += 256) k_s[i] = kb[i];
    __syncthreads();
    const int a  = tid >> 2;
    const int b0 = (tid & 3) << 4;
    float* Gw = ws + 8192 + w * 4096 + a * 64;
    for (int bb = 0; bb < 16; ++bb) {
        const int bcol = b0 + bb;
        float acc = 0.f;
        #pragma unroll
        for (int m = 0; m < 32; ++m) acc = fmaf(k_s[a * 32 + m], k_s[bcol * 32 + m], acc);
        Gw[bcol] = acc;
    }
}

// ---------------------------------------------------------------------------
// Kernel 2: chunked (n=4) WY delta-rule scan.
// One 64-lane wave per batch; lane l<32 owns M_s row l, lane l>=32 owns M_e
// row l-32 (full 32-float row in VGPRs as 16 float2).
// __launch_bounds__(64, 1): we deliberately run 1 wave/SIMD — allow the
// allocator the full VGPR budget so K[4][16] (128 VGPRs) stays resident.
// (R3 post-mortem: without this, VGPRs capped at 132 and the compiler
// rematerialized key loads just-in-time, exposing ~120-cyc LDS latency 4x
// per chunk.)
// ---------------------------------------------------------------------------
__global__ __launch_bounds__(64, 1) void scan_kernel(
    const int* __restrict__ seq, const float* __restrict__ ws,
    const float* __restrict__ Wrp, const float* __restrict__ brp,
    const float* __restrict__ Wo, const float* __restrict__ bo,
    float* __restrict__ out)
{
    const int b    = blockIdx.x;
    const int lane = threadIdx.x;      // 0..63
    const int row  = lane & 31;
    const int w    = lane >> 5;        // 0: s, 1: e

    __shared__ float4 smem4[4096];     // 64 KB: k(16K) | v(16K) | G(32K)
    __shared__ int4   tok4[512];       // 8 KB token sequence for this batch
    float* const kT = (float*)smem4;
    float* const vT = kT + 4096;
    float* const GT = kT + 8192;

    {
        const float4* ws4 = (const float4*)ws;
        for (int i = lane; i < 4096; i += 64) smem4[i] = ws4[i];
        const int4* sq4 = (const int4*)(seq + b * SEQLEN);
        #pragma unroll
        for (int i = 0; i < 8; ++i) tok4[lane + i * 64] = sq4[lane + i * 64];
    }
    __syncthreads();

    const float* kw = kT + w * 2048;
    const float* vw = vT + w * 2048;
    const float* Gw = GT + w * 4096;

    v2f M[16];
    #pragma unroll
    for (int j = 0; j < 16; ++j) { v2f z = {0.f, 0.f}; M[j] = z; }

    v2f K[4][16];
    float vv0, vv1, vv2, vv3;
    float g01, g02, g03, g12, g13, g23;

    int4 tkC = tok4[0];                // broadcast LDS reads
    int4 tkN = tok4[1];

    auto loadK = [&](int slot, int tok) {
        const float4* kp = (const float4*)(kw + tok * 32);
        #pragma unroll
        for (int j = 0; j < 8; ++j) {
            union { float4 f4; v2f h[2]; } u;
            u.f4 = kp[j];
            K[slot][2 * j]     = u.h[0];
            K[slot][2 * j + 1] = u.h[1];
        }
    };

    auto dotK = [&](const v2f (&Kt)[16]) -> float {
        v2f q0 = M[0] * Kt[0], q1 = M[1] * Kt[1], q2 = M[2] * Kt[2], q3 = M[3] * Kt[3];
        #pragma unroll
        for (int j = 4; j < 16; j += 4) {
            q0 = fma2(M[j],     Kt[j],     q0);
            q1 = fma2(M[j + 1], Kt[j + 1], q1);
            q2 = fma2(M[j + 2], Kt[j + 2], q2);
            q3 = fma2(M[j + 3], Kt[j + 3], q3);
        }
        v2f qs = (q0 + q1) + (q2 + q3);
        return qs.x + qs.y;
    };

    // prologue: chunk-0 keys / Gram scalars / values
    loadK(0, tkC.x); loadK(1, tkC.y); loadK(2, tkC.z); loadK(3, tkC.w);
    g01 = Gw[tkC.x * 64 + tkC.y]; g02 = Gw[tkC.x * 64 + tkC.z]; g03 = Gw[tkC.x * 64 + tkC.w];
    g12 = Gw[tkC.y * 64 + tkC.z]; g13 = Gw[tkC.y * 64 + tkC.w]; g23 = Gw[tkC.z * 64 + tkC.w];
    vv0 = vw[tkC.x * 32 + row]; vv1 = vw[tkC.y * 32 + row];
    vv2 = vw[tkC.z * 32 + row]; vv3 = vw[tkC.w * 32 + row];

    const float invL = 1.0f / (float)SEQLEN;
    const bool  is_e = (w == 1);

    for (int c = 0; c < 511; ++c) {
        // matvec vs chunk-start M (4 independent dots -> ILP)
        float c0 = dotK(K[0]);
        float c1 = dotK(K[1]);
        float c2 = dotK(K[2]);
        float c3 = dotK(K[3]);

        // scalar d-recurrence with Gram corrections (exact WY algebra)
        float fb = (float)(4 * c + 1) * invL;
        float f0 = is_e ? fb             : 1.0f;
        float f1 = is_e ? fb + invL      : 1.0f;
        float f2 = is_e ? fb + 2 * invL  : 1.0f;
        float f3 = is_e ? fb + 3 * invL  : 1.0f;
        float d0 = f0 * (vv0 - c0);
        float d1 = f1 * (vv1 - c1 - g01 * d0);
        float d2 = f2 * (vv2 - c2 - (g02 * d0 + g12 * d1));
        float d3 = f3 * (vv3 - c3 - ((g03 * d0 + g13 * d1) + g23 * d2));

        v2f D0 = {d0, d0}, D1 = {d1, d1}, D2 = {d2, d2}, D3 = {d3, d3};

        // axpy; each K[t] is reloaded for the NEXT chunk right after last use
        #pragma unroll
        for (int j = 0; j < 16; ++j) M[j] = fma2(D0, K[0][j], M[j]);
        loadK(0, tkN.x);
        #pragma unroll
        for (int j = 0; j < 16; ++j) M[j] = fma2(D1, K[1][j], M[j]);
        loadK(1, tkN.y);
        #pragma unroll
        for (int j = 0; j < 16; ++j) M[j] = fma2(D2, K[2][j], M[j]);
        loadK(2, tkN.z);
        #pragma unroll
        for (int j = 0; j < 16; ++j) M[j] = fma2(D3, K[3][j], M[j]);
        loadK(3, tkN.w);

        // prefetch next chunk's Gram scalars + values
        g01 = Gw[tkN.x * 64 + tkN.y]; g02 = Gw[tkN.x * 64 + tkN.z]; g03 = Gw[tkN.x * 64 + tkN.w];
        g12 = Gw[tkN.y * 64 + tkN.z]; g13 = Gw[tkN.y * 64 + tkN.w]; g23 = Gw[tkN.z * 64 + tkN.w];
        vv0 = vw[tkN.x * 32 + row]; vv1 = vw[tkN.y * 32 + row];
        vv2 = vw[tkN.z * 32 + row]; vv3 = vw[tkN.w * 32 + row];

        tkC = tkN;
        int cn = c + 2; cn = cn > 511 ? 511 : cn;
        tkN = tok4[cn];                // broadcast LDS read, 2 chunks ahead
    }

    // final partial chunk: steps 2044..2046 write; token 2047 is the query.
    // r = M_2047 . q = c3 + g03*d0 + g13*d1 + g23*d2  (no axpy needed)
    float r;
    {
        float c0 = dotK(K[0]);
        float c1 = dotK(K[1]);
        float c2 = dotK(K[2]);
        float c3 = dotK(K[3]);
        float fb = (float)(2044 + 1) * invL;
        float f0 = is_e ? fb            : 1.0f;
        float f1 = is_e ? fb + invL     : 1.0f;
        float f2 = is_e ? fb + 2 * invL : 1.0f;
        float d0 = f0 * (vv0 - c0);
        float d1 = f1 * (vv1 - c1 - g01 * d0);
        float d2 = f2 * (vv2 - c2 - (g02 * d0 + g12 * d1));
        r = c3 + (g03 * d0 + g13 * d1) + g23 * d2;
    }

    __syncthreads();
    float* r_s  = vT;          // reuse v region (no longer needed)
    float* t1_s = vT + 64;
    r_s[lane] = r;
    __syncthreads();

    // out = (r @ Wrp.T + brp) @ Wo.T + bo
    {
        float acc = brp[lane];
        #pragma unroll 8
        for (int m = 0; m < 64; ++m) acc = fmaf(Wrp[lane * 64 + m], r_s[m], acc);
        t1_s[lane] = acc;
    }
    __syncthreads();
    {
        float acc = bo[lane];
        #pragma unroll 8
        for (int m = 0; m < 64; ++m) acc = fmaf(Wo[lane * 64 + m], t1_s[m], acc);
        out[b * 64 + lane] = acc;
    }
}

extern "C" void kernel_launch(void* const* d_in, const int* in_sizes, int n_in,
                              void* d_out, int out_size, void* d_ws, size_t ws_size,
                              hipStream_t stream)
{
    const int*   seq   = (const int*)  d_in[0];
    const float* embed = (const float*)d_in[1];
    const float* W1    = (const float*)d_in[2];
    const float* b1    = (const float*)d_in[3];
    const float* W2    = (const float*)d_in[4];
    const float* b2    = (const float*)d_in[5];
    const float* ln_g  = (const float*)d_in[6];
    const float* ln_b  = (const float*)d_in[7];
    const float* Ws    = (const float*)d_in[8];
    const float* bs    = (const float*)d_in[9];
    const float* We    = (const float*)d_in[10];
    const float* be    = (const float*)d_in[11];
    const float* Wrp   = (const float*)d_in[12];
    const float* brp   = (const float*)d_in[13];
    const float* Wo    = (const float*)d_in[14];
    const float* bo    = (const float*)d_in[15];
    float* ws  = (float*)d_ws;
    float* out = (float*)d_out;

    hipLaunchKernelGGL(vocab_kernel, dim3(VOCAB), dim3(64), 0, stream,
                       embed, W1, b1, W2, b2, ln_g, ln_b, Ws, bs, We, be, ws);
    hipLaunchKernelGGL(gram_kernel, dim3(2), dim3(256), 0, stream, ws);
    hipLaunchKernelGGL(scan_kernel, dim3(BATCH), dim3(64), 0, stream,
                       seq, ws, Wrp, brp, Wo, bo, out);
}

// Round 5
// 346.564 us; speedup vs baseline: 1.3396x; 1.2027x over previous
//
#include <hip/hip_runtime.h>

typedef float v2f __attribute__((ext_vector_type(2)));

#define HIDDEN 64
#define HALFD  32
#define VOCAB  64
#define BATCH  256
#define SEQLEN 2048

static __device__ __forceinline__ v2f fma2(v2f a, v2f b, v2f c) {
    return __builtin_elementwise_fma(a, b, c);
}

// ---------------------------------------------------------------------------
// Kernel 1: per-token vocab tables.
//   ws[0    ..2047]  ks_voc [64][32]  (normalized hs)
//   ws[2048 ..4095]  ke_voc [64][32]  (normalized he)
//   ws[4096 ..6143]  vs_voc [64][32]  (raw hs)
//   ws[6144 ..8191]  ve_voc [64][32]  (raw he)
//   ws[8192 ..12287] Gs [64][64]      (written by gram_kernel)
//   ws[12288..16383] Ge [64][64]
// ---------------------------------------------------------------------------
__global__ __launch_bounds__(64) void vocab_kernel(
    const float* __restrict__ embed, const float* __restrict__ W1, const float* __restrict__ b1,
    const float* __restrict__ W2, const float* __restrict__ b2,
    const float* __restrict__ ln_g, const float* __restrict__ ln_b,
    const float* __restrict__ Ws, const float* __restrict__ bs,
    const float* __restrict__ We, const float* __restrict__ be,
    float* __restrict__ ws)
{
    const int v = blockIdx.x;
    const int tid = threadIdx.x;

    __shared__ float e_s[64];
    __shared__ float a1_s[128];
    __shared__ float h_s[64];

    e_s[tid] = embed[v * 64 + tid];
    __syncthreads();

    float acc0 = b1[tid], acc1 = b1[tid + 64];
    #pragma unroll 8
    for (int m = 0; m < 64; ++m) {
        float ev = e_s[m];
        acc0 = fmaf(ev, W1[tid * 64 + m], acc0);
        acc1 = fmaf(ev, W1[(tid + 64) * 64 + m], acc1);
    }
    a1_s[tid]      = fmaxf(acc0, 0.0f);
    a1_s[tid + 64] = fmaxf(acc1, 0.0f);
    __syncthreads();

    float ff = b2[tid];
    #pragma unroll 8
    for (int m = 0; m < 128; ++m) ff = fmaf(a1_s[m], W2[tid * 128 + m], ff);
    float x = e_s[tid] + ff;

    float s = x, s2 = x * x;
    #pragma unroll
    for (int off = 32; off >= 1; off >>= 1) {
        s  += __shfl_xor(s,  off, 64);
        s2 += __shfl_xor(s2, off, 64);
    }
    float mu  = s * (1.0f / 64.0f);
    float var = s2 * (1.0f / 64.0f) - mu * mu;
    float hval = (x - mu) * rsqrtf(var + 1e-5f) * ln_g[tid] + ln_b[tid];
    h_s[tid] = hval;
    __syncthreads();

    const int j = tid & 31;
    const bool is_s = tid < 32;
    const float* W = is_s ? Ws : We;
    float acc = is_s ? bs[j] : be[j];
    #pragma unroll 8
    for (int m = 0; m < 64; ++m) acc = fmaf(h_s[m], W[j * 64 + m], acc);

    float n2 = acc * acc;
    #pragma unroll
    for (int off = 16; off >= 1; off >>= 1) n2 += __shfl_xor(n2, off, 64);
    float norm = sqrtf(n2);
    float kn = acc / fmaxf(norm, 1e-12f);

    const int base = v * 32 + j;
    if (is_s) { ws[base]        = kn; ws[4096 + base] = acc; }
    else      { ws[2048 + base] = kn; ws[6144 + base] = acc; }
}

// ---------------------------------------------------------------------------
// Kernel 1b: Gram tables G_w[a][b] = k_w[a] . k_w[b]  (64x64 per branch)
// ---------------------------------------------------------------------------
__global__ __launch_bounds__(256) void gram_kernel(float* __restrict__ ws)
{
    const int w = blockIdx.x;        // 0: s, 1: e
    const int tid = threadIdx.x;
    __shared__ float k_s[2048];
    const float* kb = ws + w * 2048;
    for (int i = tid; i < 2048; i += 256) k_s[i] = kb[i];
    __syncthreads();
    const int a  = tid >> 2;
    const int b0 = (tid & 3) << 4;
    float* Gw = ws + 8192 + w * 4096 + a * 64;
    for (int bb = 0; bb < 16; ++bb) {
        const int bcol = b0 + bb;
        float acc = 0.f;
        #pragma unroll
        for (int m = 0; m < 32; ++m) acc = fmaf(k_s[a * 32 + m], k_s[bcol * 32 + m], acc);
        Gw[bcol] = acc;
    }
}

// ---------------------------------------------------------------------------
// Kernel 2: chunked (n=4) WY delta-rule scan, HALF-ROW SPLIT.
// 128 threads/block: wave0 owns M_s, wave1 owns M_e. Within a wave, lane
// (row, half) owns M[row][half*16 .. half*16+15] (8 v2f). Per step a lane
// loads only 4 float4 of key; full-row dots are combined with one
// shfl_xor(32) in the chunk's PARALLEL matvec phase (4 independent dots
// overlap the shuffle latency). Live set K[4][8]+M[8] (~110 VGPRs) fits the
// compiler's 132-reg budget, so chunk-ahead prefetch survives scheduling
// (R3/R4 post-mortem: bigger live sets got rematerialized into just-in-time
// LDS loads).
// ---------------------------------------------------------------------------
__global__ __launch_bounds__(128, 1) void scan_kernel(
    const int* __restrict__ seq, const float* __restrict__ ws,
    const float* __restrict__ Wrp, const float* __restrict__ brp,
    const float* __restrict__ Wo, const float* __restrict__ bo,
    float* __restrict__ out)
{
    const int b    = blockIdx.x;
    const int tid  = threadIdx.x;      // 0..127
    const int w    = tid >> 6;         // 0: s, 1: e
    const int lane = tid & 63;
    const int row  = lane & 31;
    const int half = lane >> 5;
    const int colb = half << 4;        // column base: 0 or 16

    __shared__ float4 smem4[4096];     // 64 KB: k(16K) | v(16K) | G(32K)
    __shared__ int4   tok4[512];       // 8 KB token sequence
    float* const kT = (float*)smem4;
    float* const vT = kT + 4096;
    float* const GT = kT + 8192;

    {
        const float4* ws4 = (const float4*)ws;
        for (int i = tid; i < 4096; i += 128) smem4[i] = ws4[i];
        const int4* sq4 = (const int4*)(seq + b * SEQLEN);
        #pragma unroll
        for (int i = 0; i < 4; ++i) tok4[tid + i * 128] = sq4[tid + i * 128];
    }
    __syncthreads();

    const float* kw = kT + w * 2048 + colb;   // this lane's 16-col segment
    const float* vw = vT + w * 2048;
    const float* Gw = GT + w * 4096;

    v2f M[8];
    #pragma unroll
    for (int j = 0; j < 8; ++j) { v2f z = {0.f, 0.f}; M[j] = z; }

    v2f K[4][8];
    float vv0, vv1, vv2, vv3;
    float g01, g02, g03, g12, g13, g23;

    int4 tkC = tok4[0];
    int4 tkN = tok4[1];

    auto loadK = [&](int slot, int tok) {
        const float4* kp = (const float4*)(kw + tok * 32);
        #pragma unroll
        for (int j = 0; j < 4; ++j) {
            union { float4 f4; v2f h[2]; } u;
            u.f4 = kp[j];
            K[slot][2 * j]     = u.h[0];
            K[slot][2 * j + 1] = u.h[1];
        }
    };

    // partial (16-col) dot; caller combines halves with shfl_xor
    auto dotP = [&](const v2f (&Kt)[8]) -> float {
        v2f q0 = M[0] * Kt[0], q1 = M[1] * Kt[1];
        #pragma unroll
        for (int j = 2; j < 8; j += 2) {
            q0 = fma2(M[j],     Kt[j],     q0);
            q1 = fma2(M[j + 1], Kt[j + 1], q1);
        }
        v2f qs = q0 + q1;
        return qs.x + qs.y;
    };

    // prologue: chunk-0 keys / Gram scalars / values
    loadK(0, tkC.x); loadK(1, tkC.y); loadK(2, tkC.z); loadK(3, tkC.w);
    g01 = Gw[tkC.x * 64 + tkC.y]; g02 = Gw[tkC.x * 64 + tkC.z]; g03 = Gw[tkC.x * 64 + tkC.w];
    g12 = Gw[tkC.y * 64 + tkC.z]; g13 = Gw[tkC.y * 64 + tkC.w]; g23 = Gw[tkC.z * 64 + tkC.w];
    vv0 = vw[tkC.x * 32 + row]; vv1 = vw[tkC.y * 32 + row];
    vv2 = vw[tkC.z * 32 + row]; vv3 = vw[tkC.w * 32 + row];

    const float invL = 1.0f / (float)SEQLEN;
    const bool  is_e = (w == 1);

    for (int c = 0; c < 511; ++c) {
        // matvec phase: 4 independent partial dots; shuffles overlap them
        float p0 = dotP(K[0]);
        float p1 = dotP(K[1]);
        float p2 = dotP(K[2]);
        float p3 = dotP(K[3]);
        float c0 = p0 + __shfl_xor(p0, 32, 64);
        float c1 = p1 + __shfl_xor(p1, 32, 64);
        float c2 = p2 + __shfl_xor(p2, 32, 64);
        float c3 = p3 + __shfl_xor(p3, 32, 64);

        // scalar d-recurrence with Gram corrections (exact WY algebra)
        float fb = (float)(4 * c + 1) * invL;
        float f0 = is_e ? fb             : 1.0f;
        float f1 = is_e ? fb + invL      : 1.0f;
        float f2 = is_e ? fb + 2 * invL  : 1.0f;
        float f3 = is_e ? fb + 3 * invL  : 1.0f;
        float d0 = f0 * (vv0 - c0);
        float d1 = f1 * (vv1 - c1 - g01 * d0);
        float d2 = f2 * (vv2 - c2 - (g02 * d0 + g12 * d1));
        float d3 = f3 * (vv3 - c3 - ((g03 * d0 + g13 * d1) + g23 * d2));

        v2f D0 = {d0, d0}, D1 = {d1, d1}, D2 = {d2, d2}, D3 = {d3, d3};

        // axpy; each K[t] reloaded for the NEXT chunk right after last use
        #pragma unroll
        for (int j = 0; j < 8; ++j) M[j] = fma2(D0, K[0][j], M[j]);
        loadK(0, tkN.x);
        #pragma unroll
        for (int j = 0; j < 8; ++j) M[j] = fma2(D1, K[1][j], M[j]);
        loadK(1, tkN.y);
        #pragma unroll
        for (int j = 0; j < 8; ++j) M[j] = fma2(D2, K[2][j], M[j]);
        loadK(2, tkN.z);
        #pragma unroll
        for (int j = 0; j < 8; ++j) M[j] = fma2(D3, K[3][j], M[j]);
        loadK(3, tkN.w);

        // prefetch next chunk's Gram scalars + values
        g01 = Gw[tkN.x * 64 + tkN.y]; g02 = Gw[tkN.x * 64 + tkN.z]; g03 = Gw[tkN.x * 64 + tkN.w];
        g12 = Gw[tkN.y * 64 + tkN.z]; g13 = Gw[tkN.y * 64 + tkN.w]; g23 = Gw[tkN.z * 64 + tkN.w];
        vv0 = vw[tkN.x * 32 + row]; vv1 = vw[tkN.y * 32 + row];
        vv2 = vw[tkN.z * 32 + row]; vv3 = vw[tkN.w * 32 + row];

        tkC = tkN;
        int cn = c + 2; cn = cn > 511 ? 511 : cn;
        tkN = tok4[cn];                // broadcast LDS read, 2 chunks ahead
    }

    // final partial chunk: steps 2044..2046 write; token 2047 is the query.
    // r = M_2047 . q = c3 + g03*d0 + g13*d1 + g23*d2  (no axpy needed)
    float r;
    {
        float p0 = dotP(K[0]);
        float p1 = dotP(K[1]);
        float p2 = dotP(K[2]);
        float p3 = dotP(K[3]);
        float c0 = p0 + __shfl_xor(p0, 32, 64);
        float c1 = p1 + __shfl_xor(p1, 32, 64);
        float c2 = p2 + __shfl_xor(p2, 32, 64);
        float c3 = p3 + __shfl_xor(p3, 32, 64);
        float fb = (float)(2044 + 1) * invL;
        float f0 = is_e ? fb            : 1.0f;
        float f1 = is_e ? fb + invL     : 1.0f;
        float f2 = is_e ? fb + 2 * invL : 1.0f;
        float d0 = f0 * (vv0 - c0);
        float d1 = f1 * (vv1 - c1 - g01 * d0);
        float d2 = f2 * (vv2 - c2 - (g02 * d0 + g12 * d1));
        r = c3 + (g03 * d0 + g13 * d1) + g23 * d2;
    }

    __syncthreads();
    float* r_s  = vT;          // reuse v region (no longer needed)
    float* t1_s = vT + 64;
    if (half == 0) r_s[w * 32 + row] = r;
    __syncthreads();

    // out = (r @ Wrp.T + brp) @ Wo.T + bo   (first 64 threads)
    if (tid < 64) {
        float acc = brp[tid];
        #pragma unroll 8
        for (int m = 0; m < 64; ++m) acc = fmaf(Wrp[tid * 64 + m], r_s[m], acc);
        t1_s[tid] = acc;
    }
    __syncthreads();
    if (tid < 64) {
        float acc = bo[tid];
        #pragma unroll 8
        for (int m = 0; m < 64; ++m) acc = fmaf(Wo[tid * 64 + m], t1_s[m], acc);
        out[b * 64 + tid] = acc;
    }
}

extern "C" void kernel_launch(void* const* d_in, const int* in_sizes, int n_in,
                              void* d_out, int out_size, void* d_ws, size_t ws_size,
                              hipStream_t stream)
{
    const int*   seq   = (const int*)  d_in[0];
    const float* embed = (const float*)d_in[1];
    const float* W1    = (const float*)d_in[2];
    const float* b1    = (const float*)d_in[3];
    const float* W2    = (const float*)d_in[4];
    const float* b2    = (const float*)d_in[5];
    const float* ln_g  = (const float*)d_in[6];
    const float* ln_b  = (const float*)d_in[7];
    const float* Ws    = (const float*)d_in[8];
    const float* bs    = (const float*)d_in[9];
    const float* We    = (const float*)d_in[10];
    const float* be    = (const float*)d_in[11];
    const float* Wrp   = (const float*)d_in[12];
    const float* brp   = (const float*)d_in[13];
    const float* Wo    = (const float*)d_in[14];
    const float* bo    = (const float*)d_in[15];
    float* ws  = (float*)d_ws;
    float* out = (float*)d_out;

    hipLaunchKernelGGL(vocab_kernel, dim3(VOCAB), dim3(64), 0, stream,
                       embed, W1, b1, W2, b2, ln_g, ln_b, Ws, bs, We, be, ws);
    hipLaunchKernelGGL(gram_kernel, dim3(2), dim3(256), 0, stream, ws);
    hipLaunchKernelGGL(scan_kernel, dim3(BATCH), dim3(128), 0, stream,
                       seq, ws, Wrp, brp, Wo, bo, out);
}

// Round 6
// 293.872 us; speedup vs baseline: 1.5798x; 1.1793x over previous
//
#include <hip/hip_runtime.h>

#define HIDDEN 64
#define HALFD  32
#define VOCAB  64
#define BATCH  256
#define SEQLEN 2048

// ---------------------------------------------------------------------------
// Kernel 1: per-token vocab tables (unchanged).
//   ws[0    ..2047]  ks_voc [64][32]  (normalized hs)
//   ws[2048 ..4095]  ke_voc [64][32]  (normalized he)
//   ws[4096 ..6143]  vs_voc [64][32]  (raw hs)
//   ws[6144 ..8191]  ve_voc [64][32]  (raw he)
//   ws[8192 ..12287] Gs [64][64]
//   ws[12288..16383] Ge [64][64]
// ---------------------------------------------------------------------------
__global__ __launch_bounds__(64) void vocab_kernel(
    const float* __restrict__ embed, const float* __restrict__ W1, const float* __restrict__ b1,
    const float* __restrict__ W2, const float* __restrict__ b2,
    const float* __restrict__ ln_g, const float* __restrict__ ln_b,
    const float* __restrict__ Ws, const float* __restrict__ bs,
    const float* __restrict__ We, const float* __restrict__ be,
    float* __restrict__ ws)
{
    const int v = blockIdx.x;
    const int tid = threadIdx.x;

    __shared__ float e_s[64];
    __shared__ float a1_s[128];
    __shared__ float h_s[64];

    e_s[tid] = embed[v * 64 + tid];
    __syncthreads();

    float acc0 = b1[tid], acc1 = b1[tid + 64];
    #pragma unroll 8
    for (int m = 0; m < 64; ++m) {
        float ev = e_s[m];
        acc0 = fmaf(ev, W1[tid * 64 + m], acc0);
        acc1 = fmaf(ev, W1[(tid + 64) * 64 + m], acc1);
    }
    a1_s[tid]      = fmaxf(acc0, 0.0f);
    a1_s[tid + 64] = fmaxf(acc1, 0.0f);
    __syncthreads();

    float ff = b2[tid];
    #pragma unroll 8
    for (int m = 0; m < 128; ++m) ff = fmaf(a1_s[m], W2[tid * 128 + m], ff);
    float x = e_s[tid] + ff;

    float s = x, s2 = x * x;
    #pragma unroll
    for (int off = 32; off >= 1; off >>= 1) {
        s  += __shfl_xor(s,  off, 64);
        s2 += __shfl_xor(s2, off, 64);
    }
    float mu  = s * (1.0f / 64.0f);
    float var = s2 * (1.0f / 64.0f) - mu * mu;
    float hval = (x - mu) * rsqrtf(var + 1e-5f) * ln_g[tid] + ln_b[tid];
    h_s[tid] = hval;
    __syncthreads();

    const int j = tid & 31;
    const bool is_s = tid < 32;
    const float* W = is_s ? Ws : We;
    float acc = is_s ? bs[j] : be[j];
    #pragma unroll 8
    for (int m = 0; m < 64; ++m) acc = fmaf(h_s[m], W[j * 64 + m], acc);

    float n2 = acc * acc;
    #pragma unroll
    for (int off = 16; off >= 1; off >>= 1) n2 += __shfl_xor(n2, off, 64);
    float norm = sqrtf(n2);
    float kn = acc / fmaxf(norm, 1e-12f);

    const int base = v * 32 + j;
    if (is_s) { ws[base]        = kn; ws[4096 + base] = acc; }
    else      { ws[2048 + base] = kn; ws[6144 + base] = acc; }
}

// ---------------------------------------------------------------------------
// Kernel 1b: Gram tables (unchanged).
// ---------------------------------------------------------------------------
__global__ __launch_bounds__(256) void gram_kernel(float* __restrict__ ws)
{
    const int w = blockIdx.x;
    const int tid = threadIdx.x;
    __shared__ float k_s[2048];
    const float* kb = ws + w * 2048;
    for (int i = tid; i < 2048; i += 256) k_s[i] = kb[i];
    __syncthreads();
    const int a  = tid >> 2;
    const int b0 = (tid & 3) << 4;
    float* Gw = ws + 8192 + w * 4096 + a * 64;
    for (int bb = 0; bb < 16; ++bb) {
        const int bcol = b0 + bb;
        float acc = 0.f;
        #pragma unroll
        for (int m = 0; m < 32; ++m) acc = fmaf(k_s[a * 32 + m], k_s[bcol * 32 + m], acc);
        Gw[bcol] = acc;
    }
}

// packed lower-tri index for (j,m), j<m, n=8: j-major offsets {0,7,13,18,22,25,27}
#define GIX(j,m) (((j)==0?0:(j)==1?7:(j)==2?13:(j)==3?18:(j)==4?22:(j)==5?25:27) + (m) - (j) - 1)

// ---------------------------------------------------------------------------
// Kernel 2: BACKWARD chunked (n=8) adjoint sweep — no M state at all.
// r = M_final q with M composed of chunk maps A_c = I - K W^T K^T,
// B_c = V W^T K^T. Backward: q <- q - K s, wacc[tok_i] += s_i, where
// t = K^T q and s solves the triangular WY system (same Gram algebra as
// the verified forward R3-R5 kernels). Final r = sum_tok wacc[tok] v[tok].
// Layout: 2 waves/block (wave = branch). lane = (i = lane&7 [scatter slot],
// seg = lane>>3 [4-float segment of the 32-dim]). Every lane holds k_j[seg]
// for ALL 8 j, so t-partials and the q-update are lane-local; the only
// cross-lane op is a 3-hop xor reduce of the 8 t-partials over seg.
// ---------------------------------------------------------------------------
__global__ __launch_bounds__(128) void scan_kernel(
    const int* __restrict__ seq, const float* __restrict__ ws,
    const float* __restrict__ Wrp, const float* __restrict__ brp,
    const float* __restrict__ Wo, const float* __restrict__ bo,
    float* __restrict__ out)
{
    const int b    = blockIdx.x;
    const int tid  = threadIdx.x;        // 0..127
    const int w    = tid >> 6;           // wave: 0 = s-branch, 1 = e-branch
    const int lane = tid & 63;
    const int i    = lane & 7;           // chunk-position slot (for scatter)
    const int seg  = lane >> 3;          // 4-float segment 0..7
    const bool is_e = (w == 1);

    __shared__ __align__(16) float4 tabs[4096];    // 64 KB: k|v|G
    __shared__ __align__(16) int    toklds[SEQLEN];
    __shared__ __align__(16) float  gstage[2][2][32];  // packed 28 coefs per (w, parity)
    __shared__ float wacc[2][64];
    __shared__ float r_s[64];
    __shared__ float t1_s[64];

    float* const kT = (float*)tabs;      // [w][tok][32]
    float* const vT = kT + 4096;
    float* const GT = kT + 8192;         // [w][tok][64]

    {
        const float4* ws4 = (const float4*)ws;
        for (int idx = tid; idx < 4096; idx += 128) tabs[idx] = ws4[idx];
        const int4* sq4 = (const int4*)(seq + b * SEQLEN);
        int4* tl4 = (int4*)toklds;
        #pragma unroll
        for (int idx = 0; idx < 4; ++idx) tl4[tid + idx * 128] = sq4[tid + idx * 128];
        ((float*)wacc)[tid] = 0.0f;
    }
    __syncthreads();

    const float* kw = kT + w * 2048;
    const float* Gw = GT + w * 4096;
    const int4*  tv = (const int4*)toklds;

    // lane-constant packed (j,m) decode for gram staging (lanes 0..27)
    int jdec = 0, mdec = 1;
    {
        int cnt = 0;
        #pragma unroll
        for (int jj = 0; jj < 7; ++jj)
            #pragma unroll
            for (int mm = jj + 1; mm < 8; ++mm) {
                if (cnt == lane) { jdec = jj; mdec = mm; }
                ++cnt;
            }
    }

    const float invL = 1.0f / (float)SEQLEN;

    // init q = query key (token at position 2047), this lane's 4-float segment
    float4 q;
    {
        int tokq = toklds[SEQLEN - 1];
        q = *(const float4*)(kw + tokq * 32 + (seg << 2));
    }

    // prologue: tokens + gram staging for chunk 255
    int4 tkA = tv[510], tkB = tv[511];
    if (lane < 28) {
        int tj = toklds[255 * 8 + jdec], tm = toklds[255 * 8 + mdec];
        gstage[w][255 & 1][lane] = Gw[tj * 64 + tm];
    }

    for (int c = 255; c >= 0; --c) {
        const int base = c * 8;

        // k fragments: all 8 rows at this lane's segment (addresses ready)
        float4 k0 = *(const float4*)(kw + tkA.x * 32 + (seg << 2));
        float4 k1 = *(const float4*)(kw + tkA.y * 32 + (seg << 2));
        float4 k2 = *(const float4*)(kw + tkA.z * 32 + (seg << 2));
        float4 k3 = *(const float4*)(kw + tkA.w * 32 + (seg << 2));
        float4 k4 = *(const float4*)(kw + tkB.x * 32 + (seg << 2));
        float4 k5 = *(const float4*)(kw + tkB.y * 32 + (seg << 2));
        float4 k6 = *(const float4*)(kw + tkB.z * 32 + (seg << 2));
        float4 k7 = *(const float4*)(kw + tkB.w * 32 + (seg << 2));

        // packed gram coefficients for this chunk (staged last iteration)
        float g[28];
        {
            const float* gs = &gstage[w][c & 1][0];
            #pragma unroll
            for (int n4 = 0; n4 < 7; ++n4) {
                float4 gg = *(const float4*)(gs + 4 * n4);
                g[4 * n4] = gg.x; g[4 * n4 + 1] = gg.y; g[4 * n4 + 2] = gg.z; g[4 * n4 + 3] = gg.w;
            }
        }

        // stage gram for chunk c-1 (off the critical chain)
        if (c > 0 && lane < 28) {
            int tj = toklds[base - 8 + jdec], tm = toklds[base - 8 + mdec];
            gstage[w][(c - 1) & 1][lane] = Gw[tj * 64 + tm];
        }
        // prefetch tokens for chunk c-1
        int4 nA = tkA, nB = tkB;
        if (c > 0) { nA = tv[(c - 1) * 2]; nB = tv[(c - 1) * 2 + 1]; }

        // own token for the scatter
        int tokown = toklds[base + i];

        // t partials: p_j = k_j[seg] . q[seg]
        float p0 = fmaf(k0.x, q.x, k0.z * q.z) + fmaf(k0.y, q.y, k0.w * q.w);
        float p1 = fmaf(k1.x, q.x, k1.z * q.z) + fmaf(k1.y, q.y, k1.w * q.w);
        float p2 = fmaf(k2.x, q.x, k2.z * q.z) + fmaf(k2.y, q.y, k2.w * q.w);
        float p3 = fmaf(k3.x, q.x, k3.z * q.z) + fmaf(k3.y, q.y, k3.w * q.w);
        float p4 = fmaf(k4.x, q.x, k4.z * q.z) + fmaf(k4.y, q.y, k4.w * q.w);
        float p5 = fmaf(k5.x, q.x, k5.z * q.z) + fmaf(k5.y, q.y, k5.w * q.w);
        float p6 = fmaf(k6.x, q.x, k6.z * q.z) + fmaf(k6.y, q.y, k6.w * q.w);
        float p7 = fmaf(k7.x, q.x, k7.z * q.z) + fmaf(k7.y, q.y, k7.w * q.w);

        // 3-hop xor reduce over seg (bits 3,4,5) -> full t_j in every lane
        #pragma unroll
        for (int msk = 8; msk <= 32; msk <<= 1) {
            p0 += __shfl_xor(p0, msk, 64);
            p1 += __shfl_xor(p1, msk, 64);
            p2 += __shfl_xor(p2, msk, 64);
            p3 += __shfl_xor(p3, msk, 64);
            p4 += __shfl_xor(p4, msk, 64);
            p5 += __shfl_xor(p5, msk, 64);
            p6 += __shfl_xor(p6, msk, 64);
            p7 += __shfl_xor(p7, msk, 64);
        }

        // per-step factors; position 8c+7 of chunk 255 is the query (dummy, f=0)
        float fb = (float)(base + 1) * invL;
        float f0 = is_e ? fb            : 1.0f;
        float f1 = is_e ? fb + invL     : 1.0f;
        float f2 = is_e ? fb + 2*invL   : 1.0f;
        float f3 = is_e ? fb + 3*invL   : 1.0f;
        float f4 = is_e ? fb + 4*invL   : 1.0f;
        float f5 = is_e ? fb + 5*invL   : 1.0f;
        float f6 = is_e ? fb + 6*invL   : 1.0f;
        float f7 = (c == 255) ? 0.0f : (is_e ? fb + 7*invL : 1.0f);

        // triangular solve (exact WY adjoint): s_j = f_j (t_j - sum_{m>j} g_jm s_m)
        float s7 = f7 * p7;
        float s6 = f6 * (p6 - g[GIX(6,7)] * s7);
        float s5 = f5 * ((p5 - g[GIX(5,7)] * s7) - g[GIX(5,6)] * s6);
        float s4 = f4 * (((p4 - g[GIX(4,7)] * s7) - g[GIX(4,6)] * s6) - g[GIX(4,5)] * s5);
        float s3 = f3 * ((((p3 - g[GIX(3,7)] * s7) - g[GIX(3,6)] * s6) - g[GIX(3,5)] * s5) - g[GIX(3,4)] * s4);
        float s2 = f2 * (((((p2 - g[GIX(2,7)] * s7) - g[GIX(2,6)] * s6) - g[GIX(2,5)] * s5) - g[GIX(2,4)] * s4) - g[GIX(2,3)] * s3);
        float s1 = f1 * ((((((p1 - g[GIX(1,7)] * s7) - g[GIX(1,6)] * s6) - g[GIX(1,5)] * s5) - g[GIX(1,4)] * s4) - g[GIX(1,3)] * s3) - g[GIX(1,2)] * s2);
        float s0 = f0 * (((((((p0 - g[GIX(0,7)] * s7) - g[GIX(0,6)] * s6) - g[GIX(0,5)] * s5) - g[GIX(0,4)] * s4) - g[GIX(0,3)] * s3) - g[GIX(0,2)] * s2) - g[GIX(0,1)] * s1);

        // q update: q[seg] -= sum_j k_j[seg] s_j (lane-local, two 4-deep trees)
        {
            float ax = fmaf(k0.x, s0, fmaf(k1.x, s1, fmaf(k2.x, s2, k3.x * s3)));
            float bx = fmaf(k4.x, s4, fmaf(k5.x, s5, fmaf(k6.x, s6, k7.x * s7)));
            float ay = fmaf(k0.y, s0, fmaf(k1.y, s1, fmaf(k2.y, s2, k3.y * s3)));
            float by = fmaf(k4.y, s4, fmaf(k5.y, s5, fmaf(k6.y, s6, k7.y * s7)));
            float az = fmaf(k0.z, s0, fmaf(k1.z, s1, fmaf(k2.z, s2, k3.z * s3)));
            float bz = fmaf(k4.z, s4, fmaf(k5.z, s5, fmaf(k6.z, s6, k7.z * s7)));
            float aw = fmaf(k0.w, s0, fmaf(k1.w, s1, fmaf(k2.w, s2, k3.w * s3)));
            float bw = fmaf(k4.w, s4, fmaf(k5.w, s5, fmaf(k6.w, s6, k7.w * s7)));
            q.x -= (ax + bx); q.y -= (ay + by); q.z -= (az + bz); q.w -= (aw + bw);
        }

        // scatter: accumulate per-token readout weight (one lane group)
        float sown = (i & 4) ? ((i & 2) ? ((i & 1) ? s7 : s6) : ((i & 1) ? s5 : s4))
                             : ((i & 2) ? ((i & 1) ? s3 : s2) : ((i & 1) ? s1 : s0));
        if (seg == 0) atomicAdd(&wacc[w][tokown], sown);

        tkA = nA; tkB = nB;
    }

    __syncthreads();

    // r[w][rho] = sum_tok wacc[w][tok] * v[w][tok][rho]
    if (tid < 64) {
        const int w2  = tid >> 5;
        const int rho = tid & 31;
        const float* vv = vT + w2 * 2048;
        const float* wa = &wacc[w2][0];
        float acc = 0.0f;
        #pragma unroll 8
        for (int tok = 0; tok < 64; ++tok) acc = fmaf(wa[tok], vv[tok * 32 + rho], acc);
        r_s[tid] = acc;
    }
    __syncthreads();

    // out = (r @ Wrp.T + brp) @ Wo.T + bo
    if (tid < 64) {
        float acc = brp[tid];
        #pragma unroll 8
        for (int m = 0; m < 64; ++m) acc = fmaf(Wrp[tid * 64 + m], r_s[m], acc);
        t1_s[tid] = acc;
    }
    __syncthreads();
    if (tid < 64) {
        float acc = bo[tid];
        #pragma unroll 8
        for (int m = 0; m < 64; ++m) acc = fmaf(Wo[tid * 64 + m], t1_s[m], acc);
        out[b * 64 + tid] = acc;
    }
}

extern "C" void kernel_launch(void* const* d_in, const int* in_sizes, int n_in,
                              void* d_out, int out_size, void* d_ws, size_t ws_size,
                              hipStream_t stream)
{
    const int*   seq   = (const int*)  d_in[0];
    const float* embed = (const float*)d_in[1];
    const float* W1    = (const float*)d_in[2];
    const float* b1    = (const float*)d_in[3];
    const float* W2    = (const float*)d_in[4];
    const float* b2    = (const float*)d_in[5];
    const float* ln_g  = (const float*)d_in[6];
    const float* ln_b  = (const float*)d_in[7];
    const float* Ws    = (const float*)d_in[8];
    const float* bs    = (const float*)d_in[9];
    const float* We    = (const float*)d_in[10];
    const float* be    = (const float*)d_in[11];
    const float* Wrp   = (const float*)d_in[12];
    const float* brp   = (const float*)d_in[13];
    const float* Wo    = (const float*)d_in[14];
    const float* bo    = (const float*)d_in[15];
    float* ws  = (float*)d_ws;
    float* out = (float*)d_out;

    hipLaunchKernelGGL(vocab_kernel, dim3(VOCAB), dim3(64), 0, stream,
                       embed, W1, b1, W2, b2, ln_g, ln_b, Ws, bs, We, be, ws);
    hipLaunchKernelGGL(gram_kernel, dim3(2), dim3(256), 0, stream, ws);
    hipLaunchKernelGGL(scan_kernel, dim3(BATCH), dim3(128), 0, stream,
                       seq, ws, Wrp, brp, Wo, bo, out);
}

// Round 7
// 230.166 us; speedup vs baseline: 2.0171x; 1.2768x over previous
//
#include <hip/hip_runtime.h>

#define HIDDEN 64
#define HALFD  32
#define VOCAB  64
#define BATCH  256
#define SEQLEN 2048
#define GPAD   65

#define RLF(v, sl) __int_as_float(__builtin_amdgcn_readlane(__float_as_int(v), (sl)))
#define RFL(x)     __builtin_amdgcn_readfirstlane(x)

// ---------------------------------------------------------------------------
// Kernel 1: per-token vocab tables (unchanged).
//   ws[0    ..2047]  ks_voc [64][32]  (normalized hs)
//   ws[2048 ..4095]  ke_voc [64][32]  (normalized he)
//   ws[4096 ..6143]  vs_voc [64][32]  (raw hs)
//   ws[6144 ..8191]  ve_voc [64][32]  (raw he)
//   ws[8192 ..16383] Gs,Ge [2][64][64]
// ---------------------------------------------------------------------------
__global__ __launch_bounds__(64) void vocab_kernel(
    const float* __restrict__ embed, const float* __restrict__ W1, const float* __restrict__ b1,
    const float* __restrict__ W2, const float* __restrict__ b2,
    const float* __restrict__ ln_g, const float* __restrict__ ln_b,
    const float* __restrict__ Ws, const float* __restrict__ bs,
    const float* __restrict__ We, const float* __restrict__ be,
    float* __restrict__ ws)
{
    const int v = blockIdx.x;
    const int tid = threadIdx.x;

    __shared__ float e_s[64];
    __shared__ float a1_s[128];
    __shared__ float h_s[64];

    e_s[tid] = embed[v * 64 + tid];
    __syncthreads();

    float acc0 = b1[tid], acc1 = b1[tid + 64];
    #pragma unroll 8
    for (int m = 0; m < 64; ++m) {
        float ev = e_s[m];
        acc0 = fmaf(ev, W1[tid * 64 + m], acc0);
        acc1 = fmaf(ev, W1[(tid + 64) * 64 + m], acc1);
    }
    a1_s[tid]      = fmaxf(acc0, 0.0f);
    a1_s[tid + 64] = fmaxf(acc1, 0.0f);
    __syncthreads();

    float ff = b2[tid];
    #pragma unroll 8
    for (int m = 0; m < 128; ++m) ff = fmaf(a1_s[m], W2[tid * 128 + m], ff);
    float x = e_s[tid] + ff;

    float s = x, s2 = x * x;
    #pragma unroll
    for (int off = 32; off >= 1; off >>= 1) {
        s  += __shfl_xor(s,  off, 64);
        s2 += __shfl_xor(s2, off, 64);
    }
    float mu  = s * (1.0f / 64.0f);
    float var = s2 * (1.0f / 64.0f) - mu * mu;
    float hval = (x - mu) * rsqrtf(var + 1e-5f) * ln_g[tid] + ln_b[tid];
    h_s[tid] = hval;
    __syncthreads();

    const int j = tid & 31;
    const bool is_s = tid < 32;
    const float* W = is_s ? Ws : We;
    float acc = is_s ? bs[j] : be[j];
    #pragma unroll 8
    for (int m = 0; m < 64; ++m) acc = fmaf(h_s[m], W[j * 64 + m], acc);

    float n2 = acc * acc;
    #pragma unroll
    for (int off = 16; off >= 1; off >>= 1) n2 += __shfl_xor(n2, off, 64);
    float norm = sqrtf(n2);
    float kn = acc / fmaxf(norm, 1e-12f);

    const int base = v * 32 + j;
    if (is_s) { ws[base]        = kn; ws[4096 + base] = acc; }
    else      { ws[2048 + base] = kn; ws[6144 + base] = acc; }
}

// ---------------------------------------------------------------------------
// Kernel 1b: Gram tables G_w[a][b] = k_w[a].k_w[b], unpadded [64][64] in ws.
// ---------------------------------------------------------------------------
__global__ __launch_bounds__(256) void gram_kernel(float* __restrict__ ws)
{
    const int w = blockIdx.x;
    const int tid = threadIdx.x;
    __shared__ float k_s[2048];
    const float* kb = ws + w * 2048;
    for (int i = tid; i < 2048; i += 256) k_s[i] = kb[i];
    __syncthreads();
    const int a  = tid >> 2;
    const int b0 = (tid & 3) << 4;
    float* Gw = ws + 8192 + w * 4096 + a * 64;
    for (int bb = 0; bb < 16; ++bb) {
        const int bcol = b0 + bb;
        float acc = 0.f;
        #pragma unroll
        for (int m = 0; m < 32; ++m) acc = fmaf(k_s[a * 32 + m], k_s[bcol * 32 + m], acc);
        Gw[bcol] = acc;
    }
}

// ---------------------------------------------------------------------------
// Kernel 2: GRAM-SPACE backward sweep. State per wave: u[a] = k_a . q (ONE
// float per lane, lane = vocab token), wacc[a] (one float per lane).
// Per chunk of 8: t_j = u[tok_j] via 8 one-hop bpermutes; g_jm extracted
// from resident G-row registers via v_readlane (zero DS, zero conflicts);
// tri-solve redundantly in all lanes; u -= sum_j s_j * Grow_j (lane-local
// FMAs); wacc via compare-select. G rows for chunk c-1 prefetched during
// chunk c. Final r = sum_tok wacc[tok] * v[tok] + output head.
// ---------------------------------------------------------------------------
__global__ __launch_bounds__(128) void scan_kernel(
    const int* __restrict__ seq, const float* __restrict__ ws,
    const float* __restrict__ Wrp, const float* __restrict__ brp,
    const float* __restrict__ Wo, const float* __restrict__ bo,
    float* __restrict__ out)
{
    const int b    = blockIdx.x;
    const int tid  = threadIdx.x;        // 0..127
    const int w    = tid >> 6;           // wave: 0 = s-branch, 1 = e-branch
    const int lane = tid & 63;
    const bool is_e = (w == 1);

    __shared__ float Gl[2 * 64 * GPAD];  // padded rows: bank-free stride-1 row reads
    __shared__ int   toklds[SEQLEN];
    __shared__ float wacc_s[2][64];
    __shared__ float r_s[64];
    __shared__ float t1_s[64];

    // stage: G (restride 64 -> 65) + token sequence
    {
        const float4* gsrc = (const float4*)(ws + 8192);
        for (int i4 = tid; i4 < 2048; i4 += 128) {
            float4 gv = gsrc[i4];
            int idx = i4 << 2;                  // flat [w][row][col], col%4==0
            int ww = idx >> 12, rc = idx & 4095;
            int rowi = rc >> 6, coli = rc & 63;
            float* d = &Gl[ww * (64 * GPAD) + rowi * GPAD + coli];
            d[0] = gv.x; d[1] = gv.y; d[2] = gv.z; d[3] = gv.w;
        }
        const int4* sq4 = (const int4*)(seq + b * SEQLEN);
        int4* tl4w = (int4*)toklds;
        #pragma unroll
        for (int i = 0; i < 4; ++i) tl4w[tid + i * 128] = sq4[tid + i * 128];
    }
    __syncthreads();

    const float* Gw = Gl + w * (64 * GPAD);
    const int4*  tl4 = (const int4*)toklds;

    const float invL = 1.0f / (float)SEQLEN;

    // prologue: tokens of chunk 255 (SGPR), chunk 254 (SGPR), rows of 255, u init
    int4 tA  = tl4[510], tB  = tl4[511];
    int tk0 = RFL(tA.x), tk1 = RFL(tA.y), tk2 = RFL(tA.z), tk3 = RFL(tA.w);
    int tk4 = RFL(tB.x), tk5 = RFL(tB.y), tk6 = RFL(tB.z), tk7 = RFL(tB.w);
    int4 tA1 = tl4[508], tB1 = tl4[509];
    int nk0 = RFL(tA1.x), nk1 = RFL(tA1.y), nk2 = RFL(tA1.z), nk3 = RFL(tA1.w);
    int nk4 = RFL(tB1.x), nk5 = RFL(tB1.y), nk6 = RFL(tB1.z), nk7 = RFL(tB1.w);

    float grow0 = Gw[tk0 * GPAD + lane], grow1 = Gw[tk1 * GPAD + lane];
    float grow2 = Gw[tk2 * GPAD + lane], grow3 = Gw[tk3 * GPAD + lane];
    float grow4 = Gw[tk4 * GPAD + lane], grow5 = Gw[tk5 * GPAD + lane];
    float grow6 = Gw[tk6 * GPAD + lane], grow7 = Gw[tk7 * GPAD + lane];

    float u     = Gw[tk7 * GPAD + lane];   // query token IS position 2047 = tk7 of chunk 255
    float waccv = 0.0f;

    for (int c = 255; c >= 0; --c) {
        // t_j = u[tok_j]: one-hop broadcast bpermutes (the only cross-lane ops)
        float t0 = __shfl(u, tk0, 64);
        float t1 = __shfl(u, tk1, 64);
        float t2 = __shfl(u, tk2, 64);
        float t3 = __shfl(u, tk3, 64);
        float t4 = __shfl(u, tk4, 64);
        float t5 = __shfl(u, tk5, 64);
        float t6 = __shfl(u, tk6, 64);
        float t7 = __shfl(u, tk7, 64);

        // g_jm = G[tok_j][tok_m] extracted from resident row registers (no DS)
        float g01 = RLF(grow0, tk1), g02 = RLF(grow0, tk2), g03 = RLF(grow0, tk3);
        float g04 = RLF(grow0, tk4), g05 = RLF(grow0, tk5), g06 = RLF(grow0, tk6), g07 = RLF(grow0, tk7);
        float g12 = RLF(grow1, tk2), g13 = RLF(grow1, tk3), g14 = RLF(grow1, tk4);
        float g15 = RLF(grow1, tk5), g16 = RLF(grow1, tk6), g17 = RLF(grow1, tk7);
        float g23 = RLF(grow2, tk3), g24 = RLF(grow2, tk4), g25 = RLF(grow2, tk5);
        float g26 = RLF(grow2, tk6), g27 = RLF(grow2, tk7);
        float g34 = RLF(grow3, tk4), g35 = RLF(grow3, tk5), g36 = RLF(grow3, tk6), g37 = RLF(grow3, tk7);
        float g45 = RLF(grow4, tk5), g46 = RLF(grow4, tk6), g47 = RLF(grow4, tk7);
        float g56 = RLF(grow5, tk6), g57 = RLF(grow5, tk7);
        float g67 = RLF(grow6, tk7);

        // prefetch rows for chunk c-1 (tokens already in SGPRs)
        float gn0 = Gw[nk0 * GPAD + lane], gn1 = Gw[nk1 * GPAD + lane];
        float gn2 = Gw[nk2 * GPAD + lane], gn3 = Gw[nk3 * GPAD + lane];
        float gn4 = Gw[nk4 * GPAD + lane], gn5 = Gw[nk5 * GPAD + lane];
        float gn6 = Gw[nk6 * GPAD + lane], gn7 = Gw[nk7 * GPAD + lane];
        // tokens for chunk c-2 (broadcast LDS reads)
        int cm2 = (c >= 2) ? (c - 2) : 0;
        int4 tA2 = tl4[cm2 * 2], tB2 = tl4[cm2 * 2 + 1];

        // per-step factors (position 8c+7 of chunk 255 is the query: f7 = 0)
        float fb = (float)(8 * c + 1) * invL;
        float f0 = is_e ? fb            : 1.0f;
        float f1 = is_e ? fb +     invL : 1.0f;
        float f2 = is_e ? fb + 2 * invL : 1.0f;
        float f3 = is_e ? fb + 3 * invL : 1.0f;
        float f4 = is_e ? fb + 4 * invL : 1.0f;
        float f5 = is_e ? fb + 5 * invL : 1.0f;
        float f6 = is_e ? fb + 6 * invL : 1.0f;
        float f7 = (c == 255) ? 0.0f : (is_e ? fb + 7 * invL : 1.0f);

        // triangular WY adjoint solve (all lanes redundantly)
        float s7 = f7 * t7;
        float s6 = f6 * (t6 - g67 * s7);
        float s5 = f5 * ((t5 - g57 * s7) - g56 * s6);
        float s4 = f4 * (((t4 - g47 * s7) - g46 * s6) - g45 * s5);
        float s3 = f3 * ((((t3 - g37 * s7) - g36 * s6) - g35 * s5) - g34 * s4);
        float s2 = f2 * (((((t2 - g27 * s7) - g26 * s6) - g25 * s5) - g24 * s4) - g23 * s3);
        float s1 = f1 * ((((((t1 - g17 * s7) - g16 * s6) - g15 * s5) - g14 * s4) - g13 * s3) - g12 * s2);
        float s0 = f0 * (((((((t0 - g07 * s7) - g06 * s6) - g05 * s5) - g04 * s4) - g03 * s3) - g02 * s2) - g01 * s1);

        // u[a] -= sum_j s_j * G[tok_j][a]   (lane-local, two 4-deep trees)
        {
            float A = fmaf(grow0, s0, fmaf(grow1, s1, fmaf(grow2, s2, grow3 * s3)));
            float B = fmaf(grow4, s4, fmaf(grow5, s5, fmaf(grow6, s6, grow7 * s7)));
            u -= (A + B);
        }

        // wacc[tok_j] += s_j  (lane = token, compare-select)
        waccv += (lane == tk0) ? s0 : 0.0f;
        waccv += (lane == tk1) ? s1 : 0.0f;
        waccv += (lane == tk2) ? s2 : 0.0f;
        waccv += (lane == tk3) ? s3 : 0.0f;
        waccv += (lane == tk4) ? s4 : 0.0f;
        waccv += (lane == tk5) ? s5 : 0.0f;
        waccv += (lane == tk6) ? s6 : 0.0f;
        waccv += (lane == tk7) ? s7 : 0.0f;

        // rotate pipeline
        tk0 = nk0; tk1 = nk1; tk2 = nk2; tk3 = nk3;
        tk4 = nk4; tk5 = nk5; tk6 = nk6; tk7 = nk7;
        nk0 = RFL(tA2.x); nk1 = RFL(tA2.y); nk2 = RFL(tA2.z); nk3 = RFL(tA2.w);
        nk4 = RFL(tB2.x); nk5 = RFL(tB2.y); nk6 = RFL(tB2.z); nk7 = RFL(tB2.w);
        grow0 = gn0; grow1 = gn1; grow2 = gn2; grow3 = gn3;
        grow4 = gn4; grow5 = gn5; grow6 = gn6; grow7 = gn7;
    }

    wacc_s[w][lane] = waccv;
    __syncthreads();

    // r[w2][rho] = sum_tok wacc[w2][tok] * v[w2][tok][rho]  (v from global ws)
    if (tid < 64) {
        const int w2  = tid >> 5;
        const int rho = tid & 31;
        const float* vv = ws + 4096 + w2 * 2048;
        const float* wa = &wacc_s[w2][0];
        float acc = 0.0f;
        #pragma unroll 8
        for (int tok = 0; tok < 64; ++tok) acc = fmaf(wa[tok], vv[tok * 32 + rho], acc);
        r_s[tid] = acc;
    }
    __syncthreads();

    // out = (r @ Wrp.T + brp) @ Wo.T + bo
    if (tid < 64) {
        float acc = brp[tid];
        #pragma unroll 8
        for (int m = 0; m < 64; ++m) acc = fmaf(Wrp[tid * 64 + m], r_s[m], acc);
        t1_s[tid] = acc;
    }
    __syncthreads();
    if (tid < 64) {
        float acc = bo[tid];
        #pragma unroll 8
        for (int m = 0; m < 64; ++m) acc = fmaf(Wo[tid * 64 + m], t1_s[m], acc);
        out[b * 64 + tid] = acc;
    }
}

extern "C" void kernel_launch(void* const* d_in, const int* in_sizes, int n_in,
                              void* d_out, int out_size, void* d_ws, size_t ws_size,
                              hipStream_t stream)
{
    const int*   seq   = (const int*)  d_in[0];
    const float* embed = (const float*)d_in[1];
    const float* W1    = (const float*)d_in[2];
    const float* b1    = (const float*)d_in[3];
    const float* W2    = (const float*)d_in[4];
    const float* b2    = (const float*)d_in[5];
    const float* ln_g  = (const float*)d_in[6];
    const float* ln_b  = (const float*)d_in[7];
    const float* Ws    = (const float*)d_in[8];
    const float* bs    = (const float*)d_in[9];
    const float* We    = (const float*)d_in[10];
    const float* be    = (const float*)d_in[11];
    const float* Wrp   = (const float*)d_in[12];
    const float* brp   = (const float*)d_in[13];
    const float* Wo    = (const float*)d_in[14];
    const float* bo    = (const float*)d_in[15];
    float* ws  = (float*)d_ws;
    float* out = (float*)d_out;

    hipLaunchKernelGGL(vocab_kernel, dim3(VOCAB), dim3(64), 0, stream,
                       embed, W1, b1, W2, b2, ln_g, ln_b, Ws, bs, We, be, ws);
    hipLaunchKernelGGL(gram_kernel, dim3(2), dim3(256), 0, stream, ws);
    hipLaunchKernelGGL(scan_kernel, dim3(BATCH), dim3(128), 0, stream,
                       seq, ws, Wrp, brp, Wo, bo, out);
}